// Round 1
// baseline (538.332 us; speedup 1.0000x reference)
//
#include <hip/hip_runtime.h>
#include <math.h>

#define BB 256
#define NN 200000
#define DD 128
#define SLICES 8
#define CHUNK (NN / SLICES)          // 25000
#define INV_T 14.285714285714286f    // 1/0.07

// ---------------------------------------------------------------------------
// d_ws layout:
//   [0]           int    mode flag (0 = int32 masks, 1 = uint8/bool masks)
//   [256 bytes]   float  d1[BB] then d2[BB]  (per-row densities)
// ---------------------------------------------------------------------------

__device__ __forceinline__ float dot128(const float4* __restrict__ c4,
                                        const float* __restrict__ brow) {
    const float4* b4 = (const float4*)brow;
    float acc = 0.f;
#pragma unroll
    for (int i = 0; i < 32; ++i) {
        float4 c = c4[i];
        float4 b = b4[i];
        acc = fmaf(c.x, b.x, acc);
        acc = fmaf(c.y, b.y, acc);
        acc = fmaf(c.z, b.z, acc);
        acc = fmaf(c.w, b.w, acc);
    }
    return acc;
}

// Zero per-row accumulators; detect mask dtype by scanning first 50000 words
// of mask_bg (bool-bytes pack 4 flags/word -> values like 0x0100 appear;
// int32 bools are strictly 0/1). 200000 bytes scanned: in-bounds either way.
__global__ __launch_bounds__(256) void la_init(const unsigned* __restrict__ mbg_w,
                                               int* __restrict__ flag,
                                               float* __restrict__ d12) {
    const int t = threadIdx.x;
    if (t == 0) *flag = 0;
    for (int i = t; i < 2 * BB; i += 256) d12[i] = 0.f;
    __syncthreads();
    int any = 0;
    for (int i = t; i < 50000; i += 256) any |= (mbg_w[i] > 1u) ? 1 : 0;
    if (any) atomicOr(flag, 1);
}

__global__ __launch_bounds__(256) void la_main(const float* __restrict__ codes,
                                               const float* __restrict__ bank,
                                               const void* __restrict__ mbg_v,
                                               const void* __restrict__ mint_v,
                                               const int* __restrict__ flag,
                                               float* __restrict__ d1,
                                               float* __restrict__ d2) {
    __shared__ __align__(16) float code_s[DD];
    __shared__ float red1[4], red2[4];
    __shared__ float s_scale;
    const int t = threadIdx.x;
    const int s = blockIdx.x;   // slice
    const int b = blockIdx.y;   // sample row

    // ---- stage code row into LDS, compute 1/||code|| (folded into exp scale)
    float c = 0.f;
    if (t < DD) { c = codes[b * DD + t]; code_s[t] = c; }
    float sq = c * c;
#pragma unroll
    for (int off = 32; off > 0; off >>= 1) sq += __shfl_down(sq, off, 64);
    if ((t & 63) == 0) red1[t >> 6] = sq;
    __syncthreads();
    if (t == 0) {
        float ss = red1[0] + red1[1] + red1[2] + red1[3];
        s_scale = rsqrtf(ss) * INV_T;
    }
    __syncthreads();
    const float scale = s_scale;
    const float4* c4 = (const float4*)code_s;

    float l1 = 0.f, l2 = 0.f;
    const int mode = *flag;  // uniform branch

    if (mode == 0) {
        // masks are int32 (0/1); 16B vector loads, 4 elements each
        const unsigned* mbg = (const unsigned*)mbg_v + (size_t)b * NN + (size_t)s * CHUNK;
        const unsigned* mit = (const unsigned*)mint_v + (size_t)b * NN + (size_t)s * CHUNK;
        const uint4* bg4 = (const uint4*)mbg;
        const uint4* it4 = (const uint4*)mit;
        const int nv = CHUNK / 4;  // 6250
        for (int i = t; i < nv; i += 256) {
            uint4 g = bg4[i];
            uint4 h = it4[i];
            if ((g.x | g.y | g.z | g.w | h.x | h.y | h.z | h.w) == 0u) continue;
            const int n0 = s * CHUNK + i * 4;
            unsigned gv[4] = {g.x, g.y, g.z, g.w};
            unsigned iv[4] = {h.x, h.y, h.z, h.w};
#pragma unroll
            for (int j = 0; j < 4; ++j) {
                if ((gv[j] | iv[j]) != 0u) {
                    float e = __expf(dot128(c4, bank + (size_t)(n0 + j) * DD) * scale);
                    if (gv[j]) l1 += e;
                    if (iv[j]) l2 += e;
                }
            }
        }
    } else {
        // masks are raw bool bytes; 8B vector loads (25000 % 16 != 0), 8 elems
        const unsigned char* mbg = (const unsigned char*)mbg_v + (size_t)b * NN + (size_t)s * CHUNK;
        const unsigned char* mit = (const unsigned char*)mint_v + (size_t)b * NN + (size_t)s * CHUNK;
        const uint2* bg2 = (const uint2*)mbg;
        const uint2* it2 = (const uint2*)mit;
        const int nv = CHUNK / 8;  // 3125
        for (int i = t; i < nv; i += 256) {
            uint2 g = bg2[i];
            uint2 h = it2[i];
            if ((g.x | g.y | h.x | h.y) == 0u) continue;
            const int n0 = s * CHUNK + i * 8;
            unsigned gw[2] = {g.x, g.y};
            unsigned iw[2] = {h.x, h.y};
#pragma unroll
            for (int j = 0; j < 8; ++j) {
                unsigned gb = (gw[j >> 2] >> ((j & 3) * 8)) & 0xffu;
                unsigned ib = (iw[j >> 2] >> ((j & 3) * 8)) & 0xffu;
                if ((gb | ib) != 0u) {
                    float e = __expf(dot128(c4, bank + (size_t)(n0 + j) * DD) * scale);
                    if (gb) l1 += e;
                    if (ib) l2 += e;
                }
            }
        }
    }

    // ---- block-reduce l1/l2, one atomic per block into per-row accumulators
#pragma unroll
    for (int off = 32; off > 0; off >>= 1) {
        l1 += __shfl_down(l1, off, 64);
        l2 += __shfl_down(l2, off, 64);
    }
    __syncthreads();  // red1 reuse guard
    if ((t & 63) == 0) { red1[t >> 6] = l1; red2[t >> 6] = l2; }
    __syncthreads();
    if (t == 0) {
        atomicAdd(&d1[b], red1[0] + red1[1] + red1[2] + red1[3]);
        atomicAdd(&d2[b], red2[0] + red2[1] + red2[2] + red2[3]);
    }
}

__global__ __launch_bounds__(256) void la_final(const float* __restrict__ d1,
                                                const float* __restrict__ d2,
                                                float* __restrict__ out) {
    __shared__ float red[4];
    const int t = threadIdx.x;  // == row index, BB == 256
    float v = logf(d1[t]) - logf(d2[t]);
#pragma unroll
    for (int off = 32; off > 0; off >>= 1) v += __shfl_down(v, off, 64);
    if ((t & 63) == 0) red[t >> 6] = v;
    __syncthreads();
    if (t == 0) out[0] = (red[0] + red[1] + red[2] + red[3]) / (float)BB;
}

extern "C" void kernel_launch(void* const* d_in, const int* in_sizes, int n_in,
                              void* d_out, int out_size, void* d_ws, size_t ws_size,
                              hipStream_t stream) {
    const float* codes = (const float*)d_in[0];
    const float* bank  = (const float*)d_in[1];
    const void*  mbg   = d_in[2];
    const void*  mit   = d_in[3];

    int*   flag = (int*)d_ws;
    float* d12  = (float*)((char*)d_ws + 256);  // d1[256] then d2[256]

    la_init<<<1, 256, 0, stream>>>((const unsigned*)mbg, flag, d12);
    la_main<<<dim3(SLICES, BB), 256, 0, stream>>>(codes, bank, mbg, mit, flag,
                                                  d12, d12 + BB);
    la_final<<<1, 256, 0, stream>>>(d12, d12 + BB, (float*)d_out);
}

// Round 3
// 523.521 us; speedup vs baseline: 1.0283x; 1.0283x over previous
//
#include <hip/hip_runtime.h>
#include <math.h>

#define BB 256
#define NN 200000
#define DD 128
#define INV_T 14.285714285714286f   // 1/0.07

// ---------------------------------------------------------------------------
// d_ws layout (32-bit word offsets):
//   [0]        int   mode flag (0 = int32 masks, 1 = uint8/bool masks)
//   [1]        uint  entry count
//   [64 ..]    float d1[256]
//   [320..]    float d2[256]
//   [576..]    float scale[256]      (INV_T / ||code_b||)
//   [832..]    uint  entries[]       packed (b<<18) | n   (~13.4k expected)
// ---------------------------------------------------------------------------
#define WS_FLAG 0
#define WS_CNT  1
#define WS_D1   64
#define WS_D2   320
#define WS_SC   576
#define WS_EN   832

__global__ __launch_bounds__(64) void la_zero(unsigned* __restrict__ wsu) {
    if (threadIdx.x < 2) wsu[threadIdx.x] = 0u;
}

// One block per sample row: row-norm scale, zero d1/d2, and parallel dtype
// detection (scan first 50000 words of mask_bg; packed bool bytes give words
// > 1, int32 bools are strictly 0/1).
__global__ __launch_bounds__(128) void la_prep(const float* __restrict__ codes,
                                               const unsigned* __restrict__ mbg_w,
                                               float* __restrict__ wsf) {
    __shared__ float red[2];
    const int b = blockIdx.x, t = threadIdx.x;
    float c = codes[b * DD + t];
    float sq = c * c;
#pragma unroll
    for (int off = 32; off > 0; off >>= 1) sq += __shfl_down(sq, off, 64);
    if ((t & 63) == 0) red[t >> 6] = sq;
    __syncthreads();
    if (t == 0) {
        wsf[WS_SC + b] = rsqrtf(red[0] + red[1]) * INV_T;
        wsf[WS_D1 + b] = 0.f;
        wsf[WS_D2 + b] = 0.f;
    }
    int any = 0;
    const int base = b * 196;             // 256*196 = 50176 >= 50000
    for (int i = t; i < 196; i += 128) {
        int w = base + i;
        if (w < 50000) any |= (mbg_w[w] > 1u) ? 1 : 0;
    }
    if (any) atomicOr((int*)wsf + WS_FLAG, 1);
}

// Streaming compaction of mask_bg hits. Pure bandwidth: uint4 loads,
// wave-uniform skip of all-zero wave spans, per-element ballot compaction
// with one atomicAdd per wave per hit-group.
//
// CORRECTNESS INVARIANT: every __ballot / __shfl(.,0) below must execute
// with ALL 64 lanes active. The skip is made wave-uniform by balloting the
// per-lane "any nonzero" predicate first; loop bound is wave-uniform
// (i - lane < nv) with a guarded load so a tail can never split a wave.
__global__ __launch_bounds__(256) void la_scan(const void* __restrict__ mbg_v,
                                               unsigned* __restrict__ wsu,
                                               int cap) {
    const int flag = ((volatile int*)wsu)[WS_FLAG];
    unsigned* cnt = wsu + WS_CNT;
    unsigned* ent = wsu + WS_EN;
    const unsigned lane = threadIdx.x & 63;
    const unsigned tid = blockIdx.x * blockDim.x + threadIdx.x;
    const unsigned stride = gridDim.x * blockDim.x;
    const uint4* p = (const uint4*)mbg_v;

    const int epv = (flag == 0) ? 4 : 16;            // elements per uint4
    const unsigned nv = (unsigned)BB * NN / (unsigned)epv;

    for (unsigned i = tid; i - lane < nv; i += stride) {  // wave-uniform bound
        uint4 g = make_uint4(0u, 0u, 0u, 0u);
        if (i < nv) g = p[i];
        const unsigned nz = g.x | g.y | g.z | g.w;
        if (__ballot(nz != 0u) == 0ull) continue;    // wave-uniform skip
        const unsigned e0 = i * (unsigned)epv;
        const unsigned b = e0 / NN;
        const unsigned n0 = e0 - b * NN;
        const unsigned gw[4] = {g.x, g.y, g.z, g.w};
        if (flag == 0) {
#pragma unroll
            for (int j = 0; j < 4; ++j) {
                const int hit = (gw[j] != 0u);
                const unsigned long long m = __ballot(hit);
                if (m != 0ull) {                     // wave-uniform
                    unsigned base;
                    if (lane == 0) base = atomicAdd(cnt, (unsigned)__popcll(m));
                    base = __shfl(base, 0, 64);
                    if (hit) {
                        unsigned pos = base + (unsigned)__popcll(m & ((1ull << lane) - 1ull));
                        if ((int)pos < cap) ent[pos] = (b << 18) | (n0 + (unsigned)j);
                    }
                }
            }
        } else {
#pragma unroll
            for (int j = 0; j < 16; ++j) {
                const int hit = (((gw[j >> 2] >> ((j & 3) * 8)) & 0xffu) != 0u);
                const unsigned long long m = __ballot(hit);
                if (m != 0ull) {                     // wave-uniform
                    unsigned base;
                    if (lane == 0) base = atomicAdd(cnt, (unsigned)__popcll(m));
                    base = __shfl(base, 0, 64);
                    if (hit) {
                        unsigned pos = base + (unsigned)__popcll(m & ((1ull << lane) - 1ull));
                        if ((int)pos < cap) ent[pos] = (b << 18) | (n0 + (unsigned)j);
                    }
                }
            }
        }
    }
}

// One wave per entry: cooperative 128-dot (float2/lane), shfl reduce,
// exp, accumulate d1 (always) and d2 (if mask_int gather hits).
__global__ __launch_bounds__(256) void la_pair(const float* __restrict__ codes,
                                               const float* __restrict__ bank,
                                               const void* __restrict__ mint_v,
                                               unsigned* __restrict__ wsu,
                                               int cap) {
    float* wsf = (float*)wsu;
    const int flag = ((volatile int*)wsu)[WS_FLAG];
    int cnt = (int)((volatile unsigned*)wsu)[WS_CNT];
    if (cnt > cap) cnt = cap;
    const unsigned* ent = wsu + WS_EN;
    const int lane = threadIdx.x & 63;
    const int w = (int)((blockIdx.x * blockDim.x + threadIdx.x) >> 6);
    const int nw = (int)((gridDim.x * blockDim.x) >> 6);
    const float2* c2 = (const float2*)codes;
    const float2* b2 = (const float2*)bank;

    for (int i = w; i < cnt; i += nw) {
        unsigned e = ent[i];
        unsigned b = e >> 18;
        unsigned n = e & 0x3FFFFu;
        float2 cv = c2[b * 64u + (unsigned)lane];
        float2 bv = b2[(size_t)n * 64u + (unsigned)lane];
        float d = fmaf(cv.x, bv.x, cv.y * bv.y);
#pragma unroll
        for (int off = 32; off > 0; off >>= 1) d += __shfl_down(d, off, 64);
        if (lane == 0) {
            float ev = __expf(d * wsf[WS_SC + b]);
            atomicAdd(&wsf[WS_D1 + b], ev);
            unsigned im = (flag == 0)
                ? ((const unsigned*)mint_v)[(size_t)b * NN + n]
                : (unsigned)((const unsigned char*)mint_v)[(size_t)b * NN + n];
            if (im) atomicAdd(&wsf[WS_D2 + b], ev);
        }
    }
}

__global__ __launch_bounds__(256) void la_final(const float* __restrict__ d1,
                                                const float* __restrict__ d2,
                                                float* __restrict__ out) {
    __shared__ float red[4];
    const int t = threadIdx.x;  // == row index, BB == 256
    float v = logf(d1[t]) - logf(d2[t]);
#pragma unroll
    for (int off = 32; off > 0; off >>= 1) v += __shfl_down(v, off, 64);
    if ((t & 63) == 0) red[t >> 6] = v;
    __syncthreads();
    if (t == 0) out[0] = (red[0] + red[1] + red[2] + red[3]) / (float)BB;
}

extern "C" void kernel_launch(void* const* d_in, const int* in_sizes, int n_in,
                              void* d_out, int out_size, void* d_ws, size_t ws_size,
                              hipStream_t stream) {
    const float* codes = (const float*)d_in[0];
    const float* bank  = (const float*)d_in[1];
    const void*  mbg   = d_in[2];
    const void*  mit   = d_in[3];

    unsigned* wsu = (unsigned*)d_ws;
    float*    wsf = (float*)d_ws;
    int cap = (int)(ws_size / 4) - WS_EN;
    if (cap < 0) cap = 0;

    la_zero<<<1, 64, 0, stream>>>(wsu);
    la_prep<<<BB, 128, 0, stream>>>(codes, (const unsigned*)mbg, wsf);
    la_scan<<<2048, 256, 0, stream>>>(mbg, wsu, cap);
    la_pair<<<512, 256, 0, stream>>>(codes, bank, mit, wsu, cap);
    la_final<<<1, 256, 0, stream>>>(wsf + WS_D1, wsf + WS_D2, (float*)d_out);
}

// Round 4
// 512.387 us; speedup vs baseline: 1.0506x; 1.0217x over previous
//
#include <hip/hip_runtime.h>
#include <math.h>

#define BB 256
#define NN 200000
#define DD 128
#define INV_T 14.285714285714286f   // 1/0.07
#define KUNROLL 8                   // loads in flight per thread in la_scan

// ---------------------------------------------------------------------------
// d_ws layout (32-bit word offsets):
//   [0]        int   mode flag (0 = int32 masks, 1 = uint8/bool masks)
//   [1]        uint  entry count
//   [64 ..]    float d1[256]
//   [320..]    float d2[256]
//   [576..]    float scale[256]      (INV_T / ||code_b||)
//   [832..]    uint  entries[]       packed (b<<18) | n   (~13.4k expected)
// ---------------------------------------------------------------------------
#define WS_FLAG 0
#define WS_CNT  1
#define WS_D1   64
#define WS_D2   320
#define WS_SC   576
#define WS_EN   832

__global__ __launch_bounds__(64) void la_zero(unsigned* __restrict__ wsu) {
    if (threadIdx.x < 2) wsu[threadIdx.x] = 0u;
}

// One block per sample row: row-norm scale, zero d1/d2, and parallel dtype
// detection (scan first 50000 words of mask_bg; packed bool bytes give words
// > 1, int32 bools are strictly 0/1).
__global__ __launch_bounds__(128) void la_prep(const float* __restrict__ codes,
                                               const unsigned* __restrict__ mbg_w,
                                               float* __restrict__ wsf) {
    __shared__ float red[2];
    const int b = blockIdx.x, t = threadIdx.x;
    float c = codes[b * DD + t];
    float sq = c * c;
#pragma unroll
    for (int off = 32; off > 0; off >>= 1) sq += __shfl_down(sq, off, 64);
    if ((t & 63) == 0) red[t >> 6] = sq;
    __syncthreads();
    if (t == 0) {
        wsf[WS_SC + b] = rsqrtf(red[0] + red[1]) * INV_T;
        wsf[WS_D1 + b] = 0.f;
        wsf[WS_D2 + b] = 0.f;
    }
    int any = 0;
    const int base = b * 196;             // 256*196 = 50176 >= 50000
    for (int i = t; i < 196; i += 128) {
        int w = base + i;
        if (w < 50000) any |= (mbg_w[w] > 1u) ? 1 : 0;
    }
    if (any) atomicOr((int*)wsf + WS_FLAG, 1);
}

// Streaming compaction of mask_bg hits. KUNROLL independent uint4 loads per
// thread are issued before any ballot consumes them (8x memory-level
// parallelism vs the round-3 version, which had 1 outstanding load/wave and
// ran at 8% of HBM peak).
//
// CORRECTNESS INVARIANT: every __ballot / __shfl(.,0) must execute with ALL
// 64 lanes active. Outer loop bound is wave-uniform (base - lane < nv, base
// is uniform + lane); out-of-range loads are per-lane guarded to zero (no
// cross-lane op inside the guard); all ballots run with full waves.
__global__ __launch_bounds__(256) void la_scan(const void* __restrict__ mbg_v,
                                               unsigned* __restrict__ wsu,
                                               int cap) {
    const int flag = ((volatile int*)wsu)[WS_FLAG];
    unsigned* cnt = wsu + WS_CNT;
    unsigned* ent = wsu + WS_EN;
    const unsigned lane = threadIdx.x & 63;
    const unsigned tid = blockIdx.x * blockDim.x + threadIdx.x;
    const unsigned stride = gridDim.x * blockDim.x;
    const uint4* p = (const uint4*)mbg_v;

    const int epv = (flag == 0) ? 4 : 16;            // elements per uint4
    const unsigned nv = (unsigned)BB * NN / (unsigned)epv;

    for (unsigned base = tid; base - lane < nv; base += stride * KUNROLL) {
        uint4 v[KUNROLL];
#pragma unroll
        for (int k = 0; k < KUNROLL; ++k) {
            const unsigned idx = base + (unsigned)k * stride;
            v[k] = make_uint4(0u, 0u, 0u, 0u);
            if (idx < nv) v[k] = p[idx];             // per-lane guard, no x-lane op
        }
#pragma unroll
        for (int k = 0; k < KUNROLL; ++k) {
            const unsigned nz = v[k].x | v[k].y | v[k].z | v[k].w;
            if (__ballot(nz != 0u) == 0ull) continue;   // wave-uniform skip
            const unsigned i = base + (unsigned)k * stride;
            const unsigned e0 = i * (unsigned)epv;
            const unsigned b = e0 / NN;
            const unsigned n0 = e0 - b * NN;
            const unsigned gw[4] = {v[k].x, v[k].y, v[k].z, v[k].w};
            if (flag == 0) {
#pragma unroll
                for (int j = 0; j < 4; ++j) {
                    const int hit = (gw[j] != 0u);
                    const unsigned long long m = __ballot(hit);
                    if (m != 0ull) {                 // wave-uniform
                        unsigned pos0;
                        if (lane == 0) pos0 = atomicAdd(cnt, (unsigned)__popcll(m));
                        pos0 = __shfl(pos0, 0, 64);
                        if (hit) {
                            unsigned pos = pos0 + (unsigned)__popcll(m & ((1ull << lane) - 1ull));
                            if ((int)pos < cap) ent[pos] = (b << 18) | (n0 + (unsigned)j);
                        }
                    }
                }
            } else {
#pragma unroll
                for (int j = 0; j < 16; ++j) {
                    const int hit = (((gw[j >> 2] >> ((j & 3) * 8)) & 0xffu) != 0u);
                    const unsigned long long m = __ballot(hit);
                    if (m != 0ull) {                 // wave-uniform
                        unsigned pos0;
                        if (lane == 0) pos0 = atomicAdd(cnt, (unsigned)__popcll(m));
                        pos0 = __shfl(pos0, 0, 64);
                        if (hit) {
                            unsigned pos = pos0 + (unsigned)__popcll(m & ((1ull << lane) - 1ull));
                            if ((int)pos < cap) ent[pos] = (b << 18) | (n0 + (unsigned)j);
                        }
                    }
                }
            }
        }
    }
}

// One wave per entry: cooperative 128-dot (float2/lane), shfl reduce,
// exp, accumulate d1 (always) and d2 (if mask_int gather hits).
__global__ __launch_bounds__(256) void la_pair(const float* __restrict__ codes,
                                               const float* __restrict__ bank,
                                               const void* __restrict__ mint_v,
                                               unsigned* __restrict__ wsu,
                                               int cap) {
    float* wsf = (float*)wsu;
    const int flag = ((volatile int*)wsu)[WS_FLAG];
    int cnt = (int)((volatile unsigned*)wsu)[WS_CNT];
    if (cnt > cap) cnt = cap;
    const unsigned* ent = wsu + WS_EN;
    const int lane = threadIdx.x & 63;
    const int w = (int)((blockIdx.x * blockDim.x + threadIdx.x) >> 6);
    const int nw = (int)((gridDim.x * blockDim.x) >> 6);
    const float2* c2 = (const float2*)codes;
    const float2* b2 = (const float2*)bank;

    for (int i = w; i < cnt; i += nw) {
        unsigned e = ent[i];
        unsigned b = e >> 18;
        unsigned n = e & 0x3FFFFu;
        float2 cv = c2[b * 64u + (unsigned)lane];
        float2 bv = b2[(size_t)n * 64u + (unsigned)lane];
        float d = fmaf(cv.x, bv.x, cv.y * bv.y);
#pragma unroll
        for (int off = 32; off > 0; off >>= 1) d += __shfl_down(d, off, 64);
        if (lane == 0) {
            float ev = __expf(d * wsf[WS_SC + b]);
            atomicAdd(&wsf[WS_D1 + b], ev);
            unsigned im = (flag == 0)
                ? ((const unsigned*)mint_v)[(size_t)b * NN + n]
                : (unsigned)((const unsigned char*)mint_v)[(size_t)b * NN + n];
            if (im) atomicAdd(&wsf[WS_D2 + b], ev);
        }
    }
}

__global__ __launch_bounds__(256) void la_final(const float* __restrict__ d1,
                                                const float* __restrict__ d2,
                                                float* __restrict__ out) {
    __shared__ float red[4];
    const int t = threadIdx.x;  // == row index, BB == 256
    float v = logf(d1[t]) - logf(d2[t]);
#pragma unroll
    for (int off = 32; off > 0; off >>= 1) v += __shfl_down(v, off, 64);
    if ((t & 63) == 0) red[t >> 6] = v;
    __syncthreads();
    if (t == 0) out[0] = (red[0] + red[1] + red[2] + red[3]) / (float)BB;
}

extern "C" void kernel_launch(void* const* d_in, const int* in_sizes, int n_in,
                              void* d_out, int out_size, void* d_ws, size_t ws_size,
                              hipStream_t stream) {
    const float* codes = (const float*)d_in[0];
    const float* bank  = (const float*)d_in[1];
    const void*  mbg   = d_in[2];
    const void*  mit   = d_in[3];

    unsigned* wsu = (unsigned*)d_ws;
    float*    wsf = (float*)d_ws;
    int cap = (int)(ws_size / 4) - WS_EN;
    if (cap < 0) cap = 0;

    la_zero<<<1, 64, 0, stream>>>(wsu);
    la_prep<<<BB, 128, 0, stream>>>(codes, (const unsigned*)mbg, wsf);
    la_scan<<<2048, 256, 0, stream>>>(mbg, wsu, cap);
    la_pair<<<512, 256, 0, stream>>>(codes, bank, mit, wsu, cap);
    la_final<<<1, 256, 0, stream>>>(wsf + WS_D1, wsf + WS_D2, (float*)d_out);
}

// Round 5
// 413.249 us; speedup vs baseline: 1.3027x; 1.2399x over previous
//
#include <hip/hip_runtime.h>
#include <math.h>

#define BB 256
#define NN 200000
#define DD 128
#define INV_T 14.285714285714286f   // 1/0.07
#define CAP 8192                    // LDS hit-list entries (32 KB)

// ---------------------------------------------------------------------------
// d_ws layout (32-bit word offsets):
//   [0]        int   mode flag (0 = int32 masks, 1 = uint8/bool masks)
//   [64 ..]    float d1[256]
//   [320..]    float d2[256]
// ---------------------------------------------------------------------------
#define WS_FLAG 0
#define WS_D1   64
#define WS_D2   320

__global__ __launch_bounds__(64) void la_zero(unsigned* __restrict__ wsu) {
    const unsigned t = threadIdx.x;
    if (t == 0) wsu[WS_FLAG] = 0u;
    float* wsf = (float*)wsu;
    for (unsigned i = t; i < 512; i += 64) wsf[WS_D1 + i] = 0.f;
}

// Parallel dtype detection: scan first 50000 32-bit words (= 200000 bytes,
// in-bounds under both interpretations). Packed bool bytes give word values
// > 1 (hit bytes in positions 1..3, ~51 hits in row 0); int32 bools are 0/1.
__global__ __launch_bounds__(256) void la_detect(const unsigned* __restrict__ mbg_w,
                                                 unsigned* __restrict__ wsu) {
    const unsigned g = blockIdx.x * 256u + threadIdx.x;   // 64 blocks = 16384 thr
    int any = 0;
    for (unsigned i = g; i < 50000u; i += 16384u) any |= (mbg_w[i] > 1u) ? 1 : 0;
    if (any) atomicOr((int*)wsu + WS_FLAG, 1);
}

// Wave-per-hit cooperative dot (float2/lane vs LDS-staged code row), exp,
// accumulate into per-thread partials (lane 0 holds them).
__device__ __forceinline__ void process_hits(const float* __restrict__ bank,
                                             const void* __restrict__ mint_v,
                                             const unsigned* __restrict__ s_ent,
                                             int cnt, int flag, int b,
                                             const float2* __restrict__ code2,
                                             float scale, unsigned lane,
                                             unsigned wid, float& l1, float& l2) {
    for (int i = (int)wid; i < cnt; i += 4) {
        const unsigned n = s_ent[i];
        const float2 cv = code2[lane];
        const float2 bv = ((const float2*)bank)[(size_t)n * 64u + lane];
        float d = fmaf(cv.x, bv.x, cv.y * bv.y);
#pragma unroll
        for (int off = 32; off > 0; off >>= 1) d += __shfl_down(d, off, 64);
        if (lane == 0) {
            const float e = __expf(d * scale);
            l1 += e;
            const unsigned im = (flag == 0)
                ? ((const unsigned*)mint_v)[(size_t)b * NN + n]
                : (unsigned)((const unsigned char*)mint_v)[(size_t)b * NN + n];
            if (im) l2 += e;
        }
    }
}

// Fused scan + gather. Block = (slice s, row b): b is block-uniform, so the
// code row, scale, and d1/d2 targets are uniform; hits go to an LDS list
// (no global counter atomic -- the round-3/4 limiter was ~13k serialized
// same-line global atomics, ~12 ns each, cross-XCD line ping-pong).
// Flush invariant: each iteration pushes <= 4096 entries; flush whenever
// cnt >= CAP-4096 after a post-barrier uniform snapshot => pos never
// reaches CAP. All __syncthreads sit at block-uniform points.
__global__ __launch_bounds__(256) void la_fused(const float* __restrict__ codes,
                                                const float* __restrict__ bank,
                                                const void* __restrict__ mbg_v,
                                                const void* __restrict__ mint_v,
                                                unsigned* __restrict__ wsu) {
    __shared__ __align__(16) float code_s[DD];
    __shared__ unsigned s_ent[CAP];
    __shared__ unsigned s_cnt;
    __shared__ float s_red[8];
    __shared__ float s_scale;

    const int t = threadIdx.x;
    const unsigned lane = (unsigned)(t & 63);
    const unsigned wid = (unsigned)(t >> 6);
    const int s = blockIdx.x;    // slice 0..7
    const int b = blockIdx.y;    // row 0..255
    const int flag = (int)((volatile unsigned*)wsu)[WS_FLAG];

    // ---- prologue: stage code row, block-uniform scale = INV_T/||code||
    if (t == 0) s_cnt = 0u;
    float c = (t < DD) ? codes[b * DD + t] : 0.f;
    if (t < DD) code_s[t] = c;
    float sq = c * c;
#pragma unroll
    for (int off = 32; off > 0; off >>= 1) sq += __shfl_down(sq, off, 64);
    if (lane == 0) s_red[wid] = sq;
    __syncthreads();
    if (t == 0) s_scale = rsqrtf(s_red[0] + s_red[1] + s_red[2] + s_red[3]) * INV_T;
    __syncthreads();
    const float scale = s_scale;
    const float2* code2 = (const float2*)code_s;

    float l1 = 0.f, l2 = 0.f;

    if (flag == 0) {
        // int32 masks: row = 50000 uint4, slice = 6250 uint4 (exact)
        const uint4* row = (const uint4*)((const char*)mbg_v + (size_t)b * (NN * 4)) + s * 6250;
        const int n_base = s * 25000;
        for (int it = 0; it < 7; ++it) {             // ceil(6250/1024)
            uint4 v[4];
            const int idx0 = it * 1024 + t;
#pragma unroll
            for (int k = 0; k < 4; ++k) {            // 4 loads in flight
                const int idx = idx0 + k * 256;
                v[k] = make_uint4(0u, 0u, 0u, 0u);
                if (idx < 6250) v[k] = row[idx];
            }
#pragma unroll
            for (int k = 0; k < 4; ++k) {
                const unsigned gw[4] = {v[k].x, v[k].y, v[k].z, v[k].w};
                const int idx = idx0 + k * 256;
#pragma unroll
                for (int j = 0; j < 4; ++j) {
                    if (gw[j] != 0u) {
                        unsigned pos = atomicAdd(&s_cnt, 1u);
                        if (pos < CAP) s_ent[pos] = (unsigned)(n_base + idx * 4 + j);
                    }
                }
            }
            __syncthreads();
            const int cnt = (int)s_cnt;              // uniform snapshot
            if (cnt >= CAP - 4096) {                 // never in practice
                process_hits(bank, mint_v, s_ent, cnt, flag, b, code2, scale,
                             lane, wid, l1, l2);
                __syncthreads();
                if (t == 0) s_cnt = 0u;
                __syncthreads();
            }
        }
    } else {
        // bool-byte masks: row = 12500 uint4; slice = 1563 (last 1559)
        const uint4* rowb = (const uint4*)((const char*)mbg_v + (size_t)b * NN);
        const int w0 = s * 1563;
        const int wend = (s == 7) ? 12500 : (w0 + 1563);
        for (int it = 0; it < 7; ++it) {             // ceil(1563/256)
            const int idx = w0 + it * 256 + t;
            uint4 v = make_uint4(0u, 0u, 0u, 0u);
            if (idx < wend) v = rowb[idx];
            const unsigned gw[4] = {v.x, v.y, v.z, v.w};
#pragma unroll
            for (int j = 0; j < 16; ++j) {
                if (((gw[j >> 2] >> ((j & 3) * 8)) & 0xffu) != 0u) {
                    unsigned pos = atomicAdd(&s_cnt, 1u);
                    if (pos < CAP) s_ent[pos] = (unsigned)(idx * 16 + j);
                }
            }
            __syncthreads();
            const int cnt = (int)s_cnt;              // uniform snapshot
            if (cnt >= CAP - 4096) {
                process_hits(bank, mint_v, s_ent, cnt, flag, b, code2, scale,
                             lane, wid, l1, l2);
                __syncthreads();
                if (t == 0) s_cnt = 0u;
                __syncthreads();
            }
        }
    }

    // ---- tail: process remaining hits, reduce, 2 atomics per block
    __syncthreads();
    int cnt = (int)s_cnt;
    if (cnt > CAP) cnt = CAP;
    process_hits(bank, mint_v, s_ent, cnt, flag, b, code2, scale, lane, wid, l1, l2);

#pragma unroll
    for (int off = 32; off > 0; off >>= 1) {
        l1 += __shfl_down(l1, off, 64);
        l2 += __shfl_down(l2, off, 64);
    }
    __syncthreads();
    if (lane == 0) { s_red[wid] = l1; s_red[4 + wid] = l2; }
    __syncthreads();
    if (t == 0) {
        float* wsf = (float*)wsu;
        atomicAdd(&wsf[WS_D1 + b], s_red[0] + s_red[1] + s_red[2] + s_red[3]);
        atomicAdd(&wsf[WS_D2 + b], s_red[4] + s_red[5] + s_red[6] + s_red[7]);
    }
}

__global__ __launch_bounds__(256) void la_final(const float* __restrict__ d1,
                                                const float* __restrict__ d2,
                                                float* __restrict__ out) {
    __shared__ float red[4];
    const int t = threadIdx.x;  // == row index, BB == 256
    float v = logf(d1[t]) - logf(d2[t]);
#pragma unroll
    for (int off = 32; off > 0; off >>= 1) v += __shfl_down(v, off, 64);
    if ((t & 63) == 0) red[t >> 6] = v;
    __syncthreads();
    if (t == 0) out[0] = (red[0] + red[1] + red[2] + red[3]) / (float)BB;
}

extern "C" void kernel_launch(void* const* d_in, const int* in_sizes, int n_in,
                              void* d_out, int out_size, void* d_ws, size_t ws_size,
                              hipStream_t stream) {
    const float* codes = (const float*)d_in[0];
    const float* bank  = (const float*)d_in[1];
    const void*  mbg   = d_in[2];
    const void*  mit   = d_in[3];

    unsigned* wsu = (unsigned*)d_ws;
    float*    wsf = (float*)d_ws;

    la_zero<<<1, 64, 0, stream>>>(wsu);
    la_detect<<<64, 256, 0, stream>>>((const unsigned*)mbg, wsu);
    la_fused<<<dim3(8, BB), 256, 0, stream>>>(codes, bank, mbg, mit, wsu);
    la_final<<<1, 256, 0, stream>>>(wsf + WS_D1, wsf + WS_D2, (float*)d_out);
}

// Round 6
// 409.652 us; speedup vs baseline: 1.3141x; 1.0088x over previous
//
#include <hip/hip_runtime.h>
#include <math.h>

#define BB 256
#define NN 200000
#define DD 128
#define INV_T 14.285714285714286f   // 1/0.07
#define CAP 3072                    // LDS hit-list entries (12 KB)
// Flush invariant: every scan iteration pushes <= 2048 entries (int32 path:
// 512 uint4 x 4 elems; bool path: 128 uint4 x 16 elems). Flushing whenever a
// post-barrier uniform snapshot shows cnt >= CAP-2048 guarantees pos < CAP.
#define FLUSH_AT (CAP - 2048)

// ---------------------------------------------------------------------------
// d_ws layout (32-bit word offsets):
//   [0]        int   mode flag (0 = int32 masks, 1 = uint8/bool masks)
//   [64 ..]    float d1[256]
//   [320..]    float d2[256]
// ---------------------------------------------------------------------------
#define WS_FLAG 0
#define WS_D1   64
#define WS_D2   320

__global__ __launch_bounds__(64) void la_zero(unsigned* __restrict__ wsu) {
    const unsigned t = threadIdx.x;
    if (t == 0) wsu[WS_FLAG] = 0u;
    float* wsf = (float*)wsu;
    for (unsigned i = t; i < 512; i += 64) wsf[WS_D1 + i] = 0.f;
}

// Parallel dtype detection: scan first 50000 32-bit words (= 200000 bytes,
// in-bounds under both interpretations). Packed bool bytes give word values
// > 1; int32 bools are strictly 0/1.
__global__ __launch_bounds__(256) void la_detect(const unsigned* __restrict__ mbg_w,
                                                 unsigned* __restrict__ wsu) {
    const unsigned g = blockIdx.x * 256u + threadIdx.x;   // 64 blocks = 16384 thr
    int any = 0;
    for (unsigned i = g; i < 50000u; i += 16384u) any |= (mbg_w[i] > 1u) ? 1 : 0;
    if (any) atomicOr((int*)wsu + WS_FLAG, 1);
}

// Wave-per-hit cooperative dot (float2/lane vs LDS-staged code row), exp,
// accumulate into per-thread partials (lane 0 holds them).
__device__ __forceinline__ void process_hits(const float* __restrict__ bank,
                                             const void* __restrict__ mint_v,
                                             const unsigned* __restrict__ s_ent,
                                             int cnt, int flag, int b,
                                             const float2* __restrict__ code2,
                                             float scale, unsigned lane,
                                             unsigned wid, float& l1, float& l2) {
    for (int i = (int)wid; i < cnt; i += 4) {
        const unsigned n = s_ent[i];
        const float2 cv = code2[lane];
        const float2 bv = ((const float2*)bank)[(size_t)n * 64u + lane];
        float d = fmaf(cv.x, bv.x, cv.y * bv.y);
#pragma unroll
        for (int off = 32; off > 0; off >>= 1) d += __shfl_down(d, off, 64);
        if (lane == 0) {
            const float e = __expf(d * scale);
            l1 += e;
            const unsigned im = (flag == 0)
                ? ((const unsigned*)mint_v)[(size_t)b * NN + n]
                : (unsigned)((const unsigned char*)mint_v)[(size_t)b * NN + n];
            if (im) l2 += e;
        }
    }
}

// Fused scan + gather. Block = (slice s, row b): b is block-uniform, so the
// code row, scale, and d1/d2 targets are uniform; hits go to an LDS list
// (no global counter atomic). CAP=3072 keeps LDS ~13 KB so 8 blocks/CU
// co-reside (wave-capped, 100% occupancy) vs 4 at the old CAP=8192.
// All __syncthreads sit at block-uniform points.
__global__ __launch_bounds__(256) void la_fused(const float* __restrict__ codes,
                                                const float* __restrict__ bank,
                                                const void* __restrict__ mbg_v,
                                                const void* __restrict__ mint_v,
                                                unsigned* __restrict__ wsu) {
    __shared__ __align__(16) float code_s[DD];
    __shared__ unsigned s_ent[CAP];
    __shared__ unsigned s_cnt;
    __shared__ float s_red[8];
    __shared__ float s_scale;

    const int t = threadIdx.x;
    const unsigned lane = (unsigned)(t & 63);
    const unsigned wid = (unsigned)(t >> 6);
    const int s = blockIdx.x;    // slice 0..7
    const int b = blockIdx.y;    // row 0..255
    const int flag = (int)((volatile unsigned*)wsu)[WS_FLAG];

    // ---- prologue: stage code row, block-uniform scale = INV_T/||code||
    if (t == 0) s_cnt = 0u;
    float c = (t < DD) ? codes[b * DD + t] : 0.f;
    if (t < DD) code_s[t] = c;
    float sq = c * c;
#pragma unroll
    for (int off = 32; off > 0; off >>= 1) sq += __shfl_down(sq, off, 64);
    if (lane == 0) s_red[wid] = sq;
    __syncthreads();
    if (t == 0) s_scale = rsqrtf(s_red[0] + s_red[1] + s_red[2] + s_red[3]) * INV_T;
    __syncthreads();
    const float scale = s_scale;
    const float2* code2 = (const float2*)code_s;

    float l1 = 0.f, l2 = 0.f;

    if (flag == 0) {
        // int32 masks: row = 50000 uint4, slice = 6250 uint4 (exact).
        // 13 iterations x 512 uint4 (2 per thread, both loads in flight).
        const uint4* row = (const uint4*)((const char*)mbg_v + (size_t)b * (NN * 4)) + s * 6250;
        const int n_base = s * 25000;
        for (int it = 0; it < 13; ++it) {
            const int idx0 = it * 512 + t;
            uint4 v[2];
#pragma unroll
            for (int k = 0; k < 2; ++k) {
                const int idx = idx0 + k * 256;
                v[k] = make_uint4(0u, 0u, 0u, 0u);
                if (idx < 6250) v[k] = row[idx];
            }
#pragma unroll
            for (int k = 0; k < 2; ++k) {
                const unsigned gw[4] = {v[k].x, v[k].y, v[k].z, v[k].w};
                const int idx = idx0 + k * 256;
#pragma unroll
                for (int j = 0; j < 4; ++j) {
                    if (gw[j] != 0u) {
                        unsigned pos = atomicAdd(&s_cnt, 1u);
                        if (pos < CAP) s_ent[pos] = (unsigned)(n_base + idx * 4 + j);
                    }
                }
            }
            __syncthreads();
            const int cnt = (int)s_cnt;              // uniform snapshot
            if (cnt >= FLUSH_AT) {                   // never in practice
                process_hits(bank, mint_v, s_ent, cnt, flag, b, code2, scale,
                             lane, wid, l1, l2);
                __syncthreads();
                if (t == 0) s_cnt = 0u;
                __syncthreads();
            }
        }
    } else {
        // bool-byte masks: row = 12500 uint4; slice = 1563 (last 1559).
        // 13 iterations x 128 uint4 (threads 0..127 load), 16 elems each.
        const uint4* rowb = (const uint4*)((const char*)mbg_v + (size_t)b * NN);
        const int w0 = s * 1563;
        const int wend = (s == 7) ? 12500 : (w0 + 1563);
        for (int it = 0; it < 13; ++it) {
            const int idx = w0 + it * 128 + t;
            uint4 v = make_uint4(0u, 0u, 0u, 0u);
            if (t < 128 && idx < wend) v = rowb[idx];
            const unsigned gw[4] = {v.x, v.y, v.z, v.w};
#pragma unroll
            for (int j = 0; j < 16; ++j) {
                if (((gw[j >> 2] >> ((j & 3) * 8)) & 0xffu) != 0u) {
                    unsigned pos = atomicAdd(&s_cnt, 1u);
                    if (pos < CAP) s_ent[pos] = (unsigned)(idx * 16 + j);
                }
            }
            __syncthreads();
            const int cnt = (int)s_cnt;              // uniform snapshot
            if (cnt >= FLUSH_AT) {
                process_hits(bank, mint_v, s_ent, cnt, flag, b, code2, scale,
                             lane, wid, l1, l2);
                __syncthreads();
                if (t == 0) s_cnt = 0u;
                __syncthreads();
            }
        }
    }

    // ---- tail: process remaining hits, reduce, 2 atomics per block
    __syncthreads();
    int cnt = (int)s_cnt;
    if (cnt > CAP) cnt = CAP;
    process_hits(bank, mint_v, s_ent, cnt, flag, b, code2, scale, lane, wid, l1, l2);

#pragma unroll
    for (int off = 32; off > 0; off >>= 1) {
        l1 += __shfl_down(l1, off, 64);
        l2 += __shfl_down(l2, off, 64);
    }
    __syncthreads();
    if (lane == 0) { s_red[wid] = l1; s_red[4 + wid] = l2; }
    __syncthreads();
    if (t == 0) {
        float* wsf = (float*)wsu;
        atomicAdd(&wsf[WS_D1 + b], s_red[0] + s_red[1] + s_red[2] + s_red[3]);
        atomicAdd(&wsf[WS_D2 + b], s_red[4] + s_red[5] + s_red[6] + s_red[7]);
    }
}

__global__ __launch_bounds__(256) void la_final(const float* __restrict__ d1,
                                                const float* __restrict__ d2,
                                                float* __restrict__ out) {
    __shared__ float red[4];
    const int t = threadIdx.x;  // == row index, BB == 256
    float v = logf(d1[t]) - logf(d2[t]);
#pragma unroll
    for (int off = 32; off > 0; off >>= 1) v += __shfl_down(v, off, 64);
    if ((t & 63) == 0) red[t >> 6] = v;
    __syncthreads();
    if (t == 0) out[0] = (red[0] + red[1] + red[2] + red[3]) / (float)BB;
}

extern "C" void kernel_launch(void* const* d_in, const int* in_sizes, int n_in,
                              void* d_out, int out_size, void* d_ws, size_t ws_size,
                              hipStream_t stream) {
    const float* codes = (const float*)d_in[0];
    const float* bank  = (const float*)d_in[1];
    const void*  mbg   = d_in[2];
    const void*  mit   = d_in[3];

    unsigned* wsu = (unsigned*)d_ws;
    float*    wsf = (float*)d_ws;

    la_zero<<<1, 64, 0, stream>>>(wsu);
    la_detect<<<64, 256, 0, stream>>>((const unsigned*)mbg, wsu);
    la_fused<<<dim3(8, BB), 256, 0, stream>>>(codes, bank, mbg, mit, wsu);
    la_final<<<1, 256, 0, stream>>>(wsf + WS_D1, wsf + WS_D2, (float*)d_out);
}